// Round 1
// baseline (1700.001 us; speedup 1.0000x reference)
//
#include <hip/hip_runtime.h>

#define N_TOTAL   1000000
#define N_GATHER  200000
#define M_UPDATE  131072
#define MSG_DIM   512
#define MEM_DIM   256
#define K_DIM     768
#define LN_EPS    1e-5f

typedef short bf16x8 __attribute__((ext_vector_type(8)));
typedef float f32x4  __attribute__((ext_vector_type(4)));

__device__ __forceinline__ unsigned short f2bf(float f) {
    unsigned u = __float_as_uint(f);
    unsigned r = u + 0x7FFFu + ((u >> 16) & 1u);
    return (unsigned short)(r >> 16);
}

// ---------------------------------------------------------------------------
// Pack [W_ih | W_hh] (fp32) -> bf16 in MFMA B-fragment-linear order:
// Wp[kc][t][q][r16][8]  with row = t*16+r16 (0..768), k = kc*32+q*8+j (0..768)
// k<512 comes from W_ih, k>=512 from W_hh.
// ---------------------------------------------------------------------------
__global__ void pack_w_kernel(const float* __restrict__ Wih,
                              const float* __restrict__ Whh,
                              unsigned short* __restrict__ Wp) {
    int idx = blockIdx.x * blockDim.x + threadIdx.x;   // 0..73727
    if (idx >= 73728) return;
    int kc  = idx / 3072;
    int rem = idx - kc * 3072;
    int t   = rem >> 6;
    int q   = (rem >> 4) & 3;
    int r16 = rem & 15;
    int row = t * 16 + r16;
    int k0  = kc * 32 + q * 8;
    unsigned short v[8];
#pragma unroll
    for (int j = 0; j < 8; ++j) {
        int k = k0 + j;
        float f = (k < MSG_DIM) ? Wih[(size_t)row * MSG_DIM + k]
                                : Whh[(size_t)row * MEM_DIM + (k - MSG_DIM)];
        v[j] = f2bf(f);
    }
    unsigned w0 = (unsigned)v[0] | ((unsigned)v[1] << 16);
    unsigned w1 = (unsigned)v[2] | ((unsigned)v[3] << 16);
    unsigned w2 = (unsigned)v[4] | ((unsigned)v[5] << 16);
    unsigned w3 = (unsigned)v[6] | ((unsigned)v[7] << 16);
    uint4 o = make_uint4(w0, w1, w2, w3);
    ((uint4*)Wp)[idx] = o;
}

// bias[0..512)=b_ih+b_hh (r,z) ; [512..768)=b_ih_n ; [768..1024)=b_hh_n
__global__ void pack_bias_kernel(const float* __restrict__ bih,
                                 const float* __restrict__ bhh,
                                 float* __restrict__ bias) {
    int t = threadIdx.x;
    if (t < 512) {
        bias[t] = bih[t] + bhh[t];
    } else if (t < 768) {
        bias[t]       = bih[t];   // b_ih_n at [512..768)
        bias[256 + t] = bhh[t];   // b_hh_n at [768..1024)
    }
}

// ---------------------------------------------------------------------------
// Gather memory_table rows + last_update by node_ids into out.
// ---------------------------------------------------------------------------
__global__ void gather_kernel(const float* __restrict__ mem,
                              const float* __restrict__ lu,
                              const int* __restrict__ nid,
                              float* __restrict__ out_mem,
                              float* __restrict__ out_lu) {
    int tid = threadIdx.x;
    int row = blockIdx.x * 4 + (tid >> 6);
    int c4  = tid & 63;
    int n = nid[row];
    const float4* src = (const float4*)(mem + (size_t)n * MEM_DIM);
    float4* dst = (float4*)(out_mem + (size_t)row * MEM_DIM);
    dst[c4] = src[c4];
    if (tid < 4) {
        int r2 = blockIdx.x * 4 + tid;
        out_lu[r2] = lu[nid[r2]];
    }
}

__global__ void scatter_ts_kernel(const int* __restrict__ to_upd,
                                  const float* __restrict__ ts,
                                  float* __restrict__ out_lu) {
    int j = blockIdx.x * blockDim.x + threadIdx.x;
    if (j < M_UPDATE) out_lu[to_upd[j]] = ts[j];
}

// ---------------------------------------------------------------------------
// Fused GRU + LayerNorm + scatter.
// Block: 512 threads (8 waves), BM=32 rows, full N=768 gate cols.
// Wave w: row-group rg=w>>2 (16 rows), d-chunk dh=w&3 (64 cols).
// Acc per wave: r,z,xn,hn each 4 (16x16) tiles -> 64 f32/lane.
// K loop: y=[x(512)|h(256)], 24 chunks of 32.
// ---------------------------------------------------------------------------
__global__ __launch_bounds__(512, 2) void gru_kernel(
    const float* __restrict__ mem, const float* __restrict__ msgs,
    const int* __restrict__ node_ids, const int* __restrict__ to_upd,
    const unsigned short* __restrict__ Wp, const float* __restrict__ bias,
    const float* __restrict__ gamma, const float* __restrict__ beta,
    float* __restrict__ out_mem)
{
    __shared__ __align__(16) char smem[51200];
    __shared__ int   nids[32];
    __shared__ float rowstat[64];

    unsigned short* Wl = (unsigned short*)smem;           // 48KB staged W chunk
    unsigned short* Yl = (unsigned short*)(smem + 49152); // 2KB staged y chunk
    float* hbuf = (float*)smem;                           // 32x257 f32, overlays Wl post-loop

    const int tid  = threadIdx.x;
    const int wave = tid >> 6;
    const int lane = tid & 63;
    const int rg   = wave >> 2;
    const int dh   = wave & 3;
    const int l15  = lane & 15;
    const int quad = lane >> 4;
    const int row0 = blockIdx.x * 32;

    if (tid < 32) nids[tid] = node_ids[to_upd[row0 + tid]];

    f32x4 acc[16];
#pragma unroll
    for (int i = 0; i < 16; ++i) acc[i] = (f32x4){0.f, 0.f, 0.f, 0.f};

    const uint4* Wp4 = (const uint4*)Wp;
    uint4* Wl4 = (uint4*)Wl;

    __syncthreads();   // nids visible

    for (int kc = 0; kc < 24; ++kc) {
        // --- stage W chunk (identity copy of 48KB block, 16B per thread x6) ---
#pragma unroll
        for (int s = 0; s < 6; ++s) {
            int c16 = tid + s * 512;
            Wl4[c16] = Wp4[(size_t)kc * 3072 + c16];
        }
        // --- stage y chunk (convert fp32->bf16 into A-frag-linear layout) ---
        if (tid < 256) {
            int sub = tid & 7;          // 4-float slice within the 32-k chunk
            int rl  = tid >> 3;         // local row 0..31
            int k   = kc * 32 + sub * 4;
            const float* src;
            if (k < MSG_DIM) src = msgs + (size_t)(row0 + rl) * MSG_DIM + k;
            else             src = mem  + (size_t)nids[rl] * MEM_DIM + (k - MSG_DIM);
            float4 v = *(const float4*)src;
            ushort4 b;
            b.x = f2bf(v.x); b.y = f2bf(v.y); b.z = f2bf(v.z); b.w = f2bf(v.w);
            int q = sub >> 1;
            int dstoff = (((rl >> 4) * 4 + q) * 16 + (rl & 15)) * 8 + (sub & 1) * 4;
            *(ushort4*)(Yl + dstoff) = b;
        }
        __syncthreads();

        // --- compute: 12 MFMAs per wave per chunk ---
        bf16x8 a = *(const bf16x8*)(Yl + ((rg * 4 + quad) * 16 + l15) * 8);
        int tb = dh * 4;
#pragma unroll
        for (int dt = 0; dt < 4; ++dt) {
            int t_r = tb + dt;
            bf16x8 br = *(const bf16x8*)(Wl + (((t_r)      * 4 + quad) * 16 + l15) * 8);
            bf16x8 bz = *(const bf16x8*)(Wl + (((t_r + 16) * 4 + quad) * 16 + l15) * 8);
            bf16x8 bn = *(const bf16x8*)(Wl + (((t_r + 32) * 4 + quad) * 16 + l15) * 8);
            acc[dt]     = __builtin_amdgcn_mfma_f32_16x16x32_bf16(a, br, acc[dt],     0, 0, 0);
            acc[4 + dt] = __builtin_amdgcn_mfma_f32_16x16x32_bf16(a, bz, acc[4 + dt], 0, 0, 0);
            if (kc < 16)
                acc[8 + dt]  = __builtin_amdgcn_mfma_f32_16x16x32_bf16(a, bn, acc[8 + dt],  0, 0, 0);
            else
                acc[12 + dt] = __builtin_amdgcn_mfma_f32_16x16x32_bf16(a, bn, acc[12 + dt], 0, 0, 0);
        }
        __syncthreads();
    }

    // --- gates -> hbuf (pre-LN h_new) ---
#pragma unroll
    for (int dt = 0; dt < 4; ++dt) {
        int c = dh * 64 + dt * 16 + l15;
        float brz_r = bias[c];
        float brz_z = bias[256 + c];
        float b_in  = bias[512 + c];
        float b_hn  = bias[768 + c];
#pragma unroll
        for (int i = 0; i < 4; ++i) {
            int rl = rg * 16 + quad * 4 + i;
            float R = 1.f / (1.f + __expf(-(acc[dt][i]     + brz_r)));
            float Z = 1.f / (1.f + __expf(-(acc[4 + dt][i] + brz_z)));
            float nx = acc[8 + dt][i] + b_in + R * (acc[12 + dt][i] + b_hn);
            nx = fminf(fmaxf(nx, -15.f), 15.f);
            float e = __expf(2.f * nx);
            float Nn = (e - 1.f) / (e + 1.f);
            float h = mem[(size_t)nids[rl] * MEM_DIM + c];
            hbuf[rl * 257 + c] = (1.f - Z) * Nn + Z * h;
        }
    }
    __syncthreads();

    // --- LayerNorm stats: 16 threads per row ---
    {
        int rl = tid >> 4;
        int p  = tid & 15;
        float s = 0.f, s2 = 0.f;
#pragma unroll
        for (int j = 0; j < 16; ++j) {
            float v = hbuf[rl * 257 + p + j * 16];
            s += v; s2 += v * v;
        }
#pragma unroll
        for (int o = 1; o < 16; o <<= 1) {
            s  += __shfl_xor(s,  o, 64);
            s2 += __shfl_xor(s2, o, 64);
        }
        if (p == 0) {
            float mu  = s * (1.f / 256.f);
            float var = s2 * (1.f / 256.f) - mu * mu;
            rowstat[rl]      = mu;
            rowstat[32 + rl] = rsqrtf(var + LN_EPS);
        }
    }
    __syncthreads();

    // --- normalize + scattered (coalesced per row) write ---
#pragma unroll
    for (int rep = 0; rep < 16; ++rep) {
        int idx = rep * 512 + tid;
        int rl = idx >> 8;
        int c  = idx & 255;
        float mu = rowstat[rl];
        float rs = rowstat[32 + rl];
        long long orow = to_upd[row0 + rl];
        float v = (hbuf[rl * 257 + c] - mu) * rs * gamma[c] + beta[c];
        out_mem[orow * 256 + c] = v;
    }
}

extern "C" void kernel_launch(void* const* d_in, const int* in_sizes, int n_in,
                              void* d_out, int out_size, void* d_ws, size_t ws_size,
                              hipStream_t stream) {
    const float* mem    = (const float*)d_in[0];
    const float* lu     = (const float*)d_in[1];
    const float* Wih    = (const float*)d_in[2];
    const float* Whh    = (const float*)d_in[3];
    const float* bih    = (const float*)d_in[4];
    const float* bhh    = (const float*)d_in[5];
    const float* gamma  = (const float*)d_in[6];
    const float* beta   = (const float*)d_in[7];
    const float* msgs   = (const float*)d_in[8];
    const float* ts     = (const float*)d_in[9];
    const int* node_ids = (const int*)d_in[10];
    const int* to_upd   = (const int*)d_in[11];

    float* out_mem = (float*)d_out;
    float* out_lu  = (float*)d_out + (size_t)N_GATHER * MEM_DIM;

    unsigned short* Wp = (unsigned short*)d_ws;
    float* bias = (float*)((char*)d_ws + (size_t)768 * 768 * 2);

    hipLaunchKernelGGL(pack_w_kernel,    dim3(288),   dim3(256), 0, stream, Wih, Whh, Wp);
    hipLaunchKernelGGL(pack_bias_kernel, dim3(1),     dim3(768), 0, stream, bih, bhh, bias);
    hipLaunchKernelGGL(gather_kernel,    dim3(50000), dim3(256), 0, stream, mem, lu, node_ids, out_mem, out_lu);
    hipLaunchKernelGGL(scatter_ts_kernel,dim3(512),   dim3(256), 0, stream, to_upd, ts, out_lu);
    hipLaunchKernelGGL(gru_kernel,       dim3(4096),  dim3(512), 0, stream,
                       mem, msgs, node_ids, to_upd, Wp, bias, gamma, beta, out_mem);
}